// Round 2
// baseline (1269.673 us; speedup 1.0000x reference)
//
#include <hip/hip_runtime.h>
#include <math.h>

// MultiHeadAttention: x[1,4096,1024] fp32, Wq/Wk/Wv[1024,1024], Wo[1024,1024].
// Outputs (concat in d_out): y[4096*1024] fp32, attn[8*4096*4096] fp32.
//
// R4 structure:
//   split x / transpose weights -> Q,K proj (split-bf16, fused z=2 launch),
//   V proj + transpose -> qk_exp (split QK, exp, bf16 store + rowsums) ->
//   reciprocal ->
//   pv_gemm   (y_un = expS @ V^T, K-split x4, partials in attn region) ->
//   y_reduce_scale (sum partials * invRow -> Yb bf16) ->
//   attn_norm (streaming: attn = bf2f(expS) * invRow, fp32) ->
//   Wo proj.
// Rationale (R3 counters): fused pv_norm was latency-bound (2 blocks/CU,
// MfmaUtil 3.4%, 35% HBM) -- split into high-TLP streaming + pure GEMM.
// expS bf16 scratch (268 MB) lives in ws if it fits, else old fused fp32
// fallback path.

typedef unsigned short u16;
typedef __attribute__((ext_vector_type(8))) short bf16x8;
typedef __attribute__((ext_vector_type(8))) unsigned short u16x8;
typedef __attribute__((ext_vector_type(4))) float f32x4;

#define SEQ 4096
#define FDIM 1024
#define NHEAD 8
#define DK 128
#define KSPLIT 4

__device__ __forceinline__ u16 f2bf(float f) {
  unsigned u = __float_as_uint(f);
  u += 0x7fffu + ((u >> 16) & 1u);  // round-to-nearest-even
  return (u16)(u >> 16);
}
__device__ __forceinline__ float bf2f(u16 h) {
  return __uint_as_float(((unsigned)h) << 16);
}

__device__ __forceinline__ void g2l16(const void* g, void* l) {
  __builtin_amdgcn_global_load_lds(
      (const __attribute__((address_space(1))) void*)g,
      (__attribute__((address_space(3))) void*)l, 16, 0, 0);
}

// ---------------------------------------------------------------- prep kernels

__global__ void split_f32_bf16(const float4* __restrict__ in, u16* __restrict__ ohi,
                               u16* __restrict__ olo, int n4) {
  int i = blockIdx.x * 256 + threadIdx.x;
  if (i >= n4) return;
  float4 v = in[i];
  u16 h0 = f2bf(v.x), h1 = f2bf(v.y), h2 = f2bf(v.z), h3 = f2bf(v.w);
  u16 l0 = f2bf(v.x - bf2f(h0)), l1 = f2bf(v.y - bf2f(h1));
  u16 l2 = f2bf(v.z - bf2f(h2)), l3 = f2bf(v.w - bf2f(h3));
  *(ushort4*)(ohi + 4 * (size_t)i) = make_ushort4(h0, h1, h2, h3);
  *(ushort4*)(olo + 4 * (size_t)i) = make_ushort4(l0, l1, l2, l3);
}

// out[n][k] = in[k][n], 1024x1024, optional split
__global__ void transpose_split_w(const float* __restrict__ in, u16* __restrict__ ohi,
                                  u16* __restrict__ olo, int dim, int do_split) {
  __shared__ float t[32][33];
  int tx = threadIdx.x, ty = threadIdx.y;
  int x = blockIdx.x * 32 + tx;
  int y0 = blockIdx.y * 32;
  for (int j = ty; j < 32; j += 8) t[j][tx] = in[(long)(y0 + j) * dim + x];
  __syncthreads();
  int x2 = y0 + tx;
  int y2 = blockIdx.x * 32;
  for (int j = ty; j < 32; j += 8) {
    float v = t[tx][j];
    u16 hi = f2bf(v);
    ohi[(long)(y2 + j) * dim + x2] = hi;
    if (do_split) olo[(long)(y2 + j) * dim + x2] = f2bf(v - bf2f(hi));
  }
}

__global__ void transpose_bf16(const u16* __restrict__ in, u16* __restrict__ out,
                               int rows, int cols) {
  __shared__ u16 t[32][33];
  int tx = threadIdx.x, ty = threadIdx.y;
  int x = blockIdx.x * 32 + tx;
  int y0 = blockIdx.y * 32;
  for (int j = ty; j < 32; j += 8) t[j][tx] = in[(long)(y0 + j) * cols + x];
  __syncthreads();
  int x2 = y0 + tx;
  int y2 = blockIdx.x * 32;
  for (int j = ty; j < 32; j += 8) out[(long)(y2 + j) * rows + x2] = t[tx][j];
}

__global__ void reciprocal_k(const float* __restrict__ in, float* __restrict__ out, int n) {
  int i = blockIdx.x * 256 + threadIdx.x;
  if (i < n) out[i] = 1.0f / in[i];
}

// ---------------------------------------------------------------- projection GEMM (C = A * B^T)
// EPI: 0 = fp32 store, 1 = bf16 store, 2 = split bf16 store
template <int BK, bool SPLIT, int EPI>
__global__ __launch_bounds__(256, 2) void gemm_bt(
    const u16* Ahi_, const u16* Alo_,
    const u16* Bhi_, const u16* Blo_,
    void* C0, void* C1,
    int Kdim, int lda, int ldb, int ldc,
    long aStrH, long bStrH, long cStrH) {
  constexpr int LDSN = 128 * BK;
  __shared__ u16 sAhi[LDSN];
  __shared__ u16 sBhi[LDSN];
  __shared__ u16 sAlo[SPLIT ? LDSN : 2];
  __shared__ u16 sBlo[SPLIT ? LDSN : 2];

  const int tid = threadIdx.x;
  const int lane = tid & 63;
  const int wave = tid >> 6;
  const int wr = wave >> 1, wc = wave & 1;
  const int quad = lane >> 4, l16 = lane & 15;
  const int h = blockIdx.z;
  const long bm = (long)blockIdx.y * 128;
  const long bn = (long)blockIdx.x * 128;

  const u16* Ahi = Ahi_ + (long)h * aStrH;
  const u16* Alo = SPLIT ? (Alo_ + (long)h * aStrH) : nullptr;
  const u16* Bhi = Bhi_ + (long)h * bStrH;
  const u16* Blo = SPLIT ? (Blo_ + (long)h * bStrH) : nullptr;

  f32x4 acc[4][4];
#pragma unroll
  for (int i = 0; i < 4; i++)
#pragma unroll
    for (int j = 0; j < 4; j++) acc[i][j] = (f32x4)0.0f;

  for (int k0 = 0; k0 < Kdim; k0 += BK) {
    constexpr int GR = (128 * BK) / (256 * 8);
#pragma unroll
    for (int r = 0; r < GR; ++r) {
      int e = (r * 256 + tid) * 8;
      int row = e / BK, col = e % BK;
      long ga = (bm + row) * (long)lda + k0 + col;
      long gb = (bn + row) * (long)ldb + k0 + col;
      g2l16(Ahi + ga, (char*)sAhi + (size_t)e * 2);
      g2l16(Bhi + gb, (char*)sBhi + (size_t)e * 2);
      if constexpr (SPLIT) {
        g2l16(Alo + ga, (char*)sAlo + (size_t)e * 2);
        g2l16(Blo + gb, (char*)sBlo + (size_t)e * 2);
      }
    }
    __syncthreads();

#pragma unroll
    for (int ks = 0; ks < BK; ks += 32) {
      bf16x8 aH[4], bH[4];
      bf16x8 aL[SPLIT ? 4 : 1], bL[SPLIT ? 4 : 1];
#pragma unroll
      for (int mi = 0; mi < 4; mi++) {
        int off = (wr * 64 + mi * 16 + l16) * BK + ks + quad * 8;
        aH[mi] = *(const bf16x8*)&sAhi[off];
        if constexpr (SPLIT) aL[mi] = *(const bf16x8*)&sAlo[off];
      }
#pragma unroll
      for (int ni = 0; ni < 4; ni++) {
        int off = (wc * 64 + ni * 16 + l16) * BK + ks + quad * 8;
        bH[ni] = *(const bf16x8*)&sBhi[off];
        if constexpr (SPLIT) bL[ni] = *(const bf16x8*)&sBlo[off];
      }
#pragma unroll
      for (int mi = 0; mi < 4; mi++)
#pragma unroll
        for (int ni = 0; ni < 4; ni++) {
          acc[mi][ni] = __builtin_amdgcn_mfma_f32_16x16x32_bf16(aH[mi], bH[ni], acc[mi][ni], 0, 0, 0);
          if constexpr (SPLIT) {
            acc[mi][ni] = __builtin_amdgcn_mfma_f32_16x16x32_bf16(aH[mi], bL[ni], acc[mi][ni], 0, 0, 0);
            acc[mi][ni] = __builtin_amdgcn_mfma_f32_16x16x32_bf16(aL[mi], bH[ni], acc[mi][ni], 0, 0, 0);
          }
        }
    }
    __syncthreads();
  }

  const long rowB = bm + wr * 64;
  const long colB = bn + wc * 64;
  if constexpr (EPI == 2) {
    u16* Chi = (u16*)C0 + (long)h * cStrH;
    u16* Clo = (u16*)C1 + (long)h * cStrH;
#pragma unroll
    for (int mi = 0; mi < 4; mi++)
#pragma unroll
      for (int ni = 0; ni < 4; ni++) {
        long col = colB + ni * 16 + l16;
#pragma unroll
        for (int r = 0; r < 4; r++) {
          long idx = (rowB + mi * 16 + quad * 4 + r) * (long)ldc + col;
          float v = acc[mi][ni][r];
          u16 hi = f2bf(v);
          Chi[idx] = hi;
          Clo[idx] = f2bf(v - bf2f(hi));
        }
      }
  } else if constexpr (EPI == 1) {
    u16* C = (u16*)C0 + (long)h * cStrH;
#pragma unroll
    for (int mi = 0; mi < 4; mi++)
#pragma unroll
      for (int ni = 0; ni < 4; ni++) {
        long col = colB + ni * 16 + l16;
#pragma unroll
        for (int r = 0; r < 4; r++)
          C[(rowB + mi * 16 + quad * 4 + r) * (long)ldc + col] = f2bf(acc[mi][ni][r]);
      }
  } else {
    float* C = (float*)C0 + (long)h * cStrH;
#pragma unroll
    for (int mi = 0; mi < 4; mi++)
#pragma unroll
      for (int ni = 0; ni < 4; ni++) {
        long col = colB + ni * 16 + l16;
#pragma unroll
        for (int r = 0; r < 4; r++)
          C[(rowB + mi * 16 + quad * 4 + r) * (long)ldc + col] = acc[mi][ni][r];
      }
  }
}

// ---------------------------------------------------------------- QK^T + exp
// S = exp(scale * Q K^T) per head; stores bf16 (or fp32 fallback) + rowsums.
// Q,K: [4096][1024] split bf16; head h = cols [h*128, h*128+128).
template <bool BF16S>
__global__ __launch_bounds__(256, 2) void qk_exp(
    const u16* __restrict__ Qhi, const u16* __restrict__ Qlo,
    const u16* __restrict__ Khi, const u16* __restrict__ Klo,
    void* __restrict__ outE, float* __restrict__ rowSum, float scale) {
  __shared__ u16 smem[32768];  // 64 KB: staging; first 32 KB reused as P-buf
  u16* sQh = smem;
  u16* sQl = smem + 8192;
  u16* sKh = smem + 16384;
  u16* sKl = smem + 24576;

  const int tid = threadIdx.x;
  const int lane = tid & 63, wave = tid >> 6;
  const int wr = wave >> 1, wc = wave & 1;
  const int quad = lane >> 4, l16 = lane & 15;
  const int h = blockIdx.z;
  const int bm = blockIdx.y * 128, bn = blockIdx.x * 128;
  const int colOff = h * DK;

  f32x4 acc[4][4];
#pragma unroll
  for (int i = 0; i < 4; i++)
#pragma unroll
    for (int j = 0; j < 4; j++) acc[i][j] = (f32x4)0.0f;

  for (int k0 = 0; k0 < DK; k0 += 64) {
#pragma unroll
    for (int r = 0; r < 4; ++r) {
      int e = (r * 256 + tid) * 8;
      int row = e >> 6, col = e & 63;
      long gq = (long)(bm + row) * FDIM + colOff + k0 + col;
      long gk = (long)(bn + row) * FDIM + colOff + k0 + col;
      g2l16(Qhi + gq, (char*)sQh + (size_t)e * 2);
      g2l16(Qlo + gq, (char*)sQl + (size_t)e * 2);
      g2l16(Khi + gk, (char*)sKh + (size_t)e * 2);
      g2l16(Klo + gk, (char*)sKl + (size_t)e * 2);
    }
    __syncthreads();
#pragma unroll
    for (int ks = 0; ks < 64; ks += 32) {
      bf16x8 aH[4], aL[4], bH[4], bL[4];
#pragma unroll
      for (int i = 0; i < 4; i++) {
        int offA = (wr * 64 + i * 16 + l16) * 64 + ks + quad * 8;
        int offB = (wc * 64 + i * 16 + l16) * 64 + ks + quad * 8;
        aH[i] = *(const bf16x8*)&sQh[offA];
        aL[i] = *(const bf16x8*)&sQl[offA];
        bH[i] = *(const bf16x8*)&sKh[offB];
        bL[i] = *(const bf16x8*)&sKl[offB];
      }
#pragma unroll
      for (int mi = 0; mi < 4; mi++)
#pragma unroll
        for (int ni = 0; ni < 4; ni++) {
          acc[mi][ni] = __builtin_amdgcn_mfma_f32_16x16x32_bf16(aH[mi], bH[ni], acc[mi][ni], 0, 0, 0);
          acc[mi][ni] = __builtin_amdgcn_mfma_f32_16x16x32_bf16(aH[mi], bL[ni], acc[mi][ni], 0, 0, 0);
          acc[mi][ni] = __builtin_amdgcn_mfma_f32_16x16x32_bf16(aL[mi], bH[ni], acc[mi][ni], 0, 0, 0);
        }
    }
    __syncthreads();
  }

  // exp in place + per-row sums (shfl over the 16 col-lanes, atomic per block)
#pragma unroll
  for (int mi = 0; mi < 4; mi++) {
    f32x4 rs = (f32x4)0.0f;
#pragma unroll
    for (int ni = 0; ni < 4; ni++)
#pragma unroll
      for (int r = 0; r < 4; r++) {
        float e = __expf(acc[mi][ni][r] * scale);
        acc[mi][ni][r] = e;
        rs[r] += e;
      }
#pragma unroll
    for (int m = 1; m < 16; m <<= 1) {
      rs[0] += __shfl_xor(rs[0], m);
      rs[1] += __shfl_xor(rs[1], m);
      rs[2] += __shfl_xor(rs[2], m);
      rs[3] += __shfl_xor(rs[3], m);
    }
    if (l16 == 0) {
      int rbase = h * SEQ + bm + wr * 64 + mi * 16 + quad * 4;
#pragma unroll
      for (int r = 0; r < 4; r++) atomicAdd(&rowSum[rbase + r], rs[r]);
    }
  }

  // transpose tile through LDS for vectorized stores
  u16* P = smem;  // 128x128 bf16 = 32 KB (staging no longer needed)
#pragma unroll
  for (int mi = 0; mi < 4; mi++)
#pragma unroll
    for (int ni = 0; ni < 4; ni++)
#pragma unroll
      for (int r = 0; r < 4; r++)
        P[(wr * 64 + mi * 16 + quad * 4 + r) * 128 + wc * 64 + ni * 16 + l16] =
            f2bf(acc[mi][ni][r]);
  __syncthreads();

  if constexpr (BF16S) {
    u16* out = (u16*)outE + ((long)h << 24);
#pragma unroll
    for (int j = 0; j < 8; ++j) {
      int e = (j * 256 + tid) * 8;
      int row = e >> 7, col = e & 127;
      long g = (long)(bm + row) * SEQ + bn + col;
      *(uint4*)(out + g) = *(const uint4*)(P + e);
    }
  } else {
    float* out = (float*)outE + ((long)h << 24);
#pragma unroll
    for (int j = 0; j < 16; ++j) {
      int e = (j * 256 + tid) * 4;
      int row = e >> 7, col = e & 127;
      long g = (long)(bm + row) * SEQ + bn + col;
      ushort4 u = *(const ushort4*)(P + e);
      *(float4*)(out + g) = make_float4(bf2f(u.x), bf2f(u.y), bf2f(u.z), bf2f(u.w));
    }
  }
}

// ---------------------------------------------------------------- R4: PV GEMM (bf16s path)
// y_part[ks] = expS(h)[128-row tile][K-chunk] @ Vt(h)^T  (un-normalized P).
// Grid (KSPLIT, 32, 8) = 1024 blocks -> 4 blocks/CU: latency hidden by TLP.
__global__ __launch_bounds__(256, 4) void pv_gemm(
    const u16* __restrict__ expS, const u16* __restrict__ Vt,
    float* __restrict__ ypart) {
  __shared__ u16 sA[128 * 64];  // 16 KB: P tile (128 rows x 64 k)
  __shared__ u16 sB[128 * 64];  // 16 KB: Vt tile (128 dk x 64 k)
  const int tid = threadIdx.x;
  const int lane = tid & 63, wave = tid >> 6;
  const int wr = wave >> 1, wc = wave & 1;
  const int quad = lane >> 4, l16 = lane & 15;
  const int h = blockIdx.z;
  const long bm = (long)blockIdx.y * 128;
  const int kBase = blockIdx.x * (SEQ / KSPLIT);

  const u16* A = expS + ((long)h << 24);   // [4096][4096] bf16
  const u16* B = Vt + (long)h * DK * SEQ;  // [128][4096] bf16

  f32x4 acc[4][4];
#pragma unroll
  for (int i = 0; i < 4; i++)
#pragma unroll
    for (int j = 0; j < 4; j++) acc[i][j] = (f32x4)0.0f;

  for (int k0 = kBase; k0 < kBase + SEQ / KSPLIT; k0 += 64) {
#pragma unroll
    for (int r = 0; r < 4; ++r) {
      int e = (r * 256 + tid) * 8;
      int row = e >> 6, col = e & 63;
      g2l16(A + (bm + row) * (long)SEQ + k0 + col, (char*)sA + (size_t)e * 2);
      g2l16(B + (long)row * SEQ + k0 + col, (char*)sB + (size_t)e * 2);
    }
    __syncthreads();
#pragma unroll
    for (int ks = 0; ks < 64; ks += 32) {
      bf16x8 a[4], b[4];
#pragma unroll
      for (int mi = 0; mi < 4; mi++)
        a[mi] = *(const bf16x8*)&sA[(wr * 64 + mi * 16 + l16) * 64 + ks + quad * 8];
#pragma unroll
      for (int ni = 0; ni < 4; ni++)
        b[ni] = *(const bf16x8*)&sB[(wc * 64 + ni * 16 + l16) * 64 + ks + quad * 8];
#pragma unroll
      for (int mi = 0; mi < 4; mi++)
#pragma unroll
        for (int ni = 0; ni < 4; ni++)
          acc[mi][ni] = __builtin_amdgcn_mfma_f32_16x16x32_bf16(a[mi], b[ni], acc[mi][ni], 0, 0, 0);
    }
    __syncthreads();
  }

  float* out = ypart + (long)blockIdx.x * ((long)SEQ * FDIM);
#pragma unroll
  for (int mi = 0; mi < 4; mi++)
#pragma unroll
    for (int ni = 0; ni < 4; ni++) {
      int col = h * DK + wc * 64 + ni * 16 + l16;
#pragma unroll
      for (int r = 0; r < 4; r++) {
        long row = bm + wr * 64 + mi * 16 + quad * 4 + r;
        out[row * (long)FDIM + col] = acc[mi][ni][r];
      }
    }
}

// Yb[s][f] = bf16( invRow[(f>>7)*SEQ + s] * sum_ks ypart[ks][s][f] )
__global__ void y_reduce_scale(const float* __restrict__ ypart,
                               const float* __restrict__ invRow,
                               u16* __restrict__ Yb) {
  long i = ((long)blockIdx.x * 256 + threadIdx.x) * 4;
  int s = (int)(i >> 10);
  int f = (int)(i & 1023);
  float inv = invRow[(f >> 7) * SEQ + s];
  const long NP = (long)SEQ * FDIM;
  f32x4 v = *(const f32x4*)(ypart + i);
#pragma unroll
  for (int ks = 1; ks < KSPLIT; ks++) v = v + *(const f32x4*)(ypart + ks * NP + i);
  *(ushort4*)(Yb + i) =
      make_ushort4(f2bf(v[0] * inv), f2bf(v[1] * inv), f2bf(v[2] * inv), f2bf(v[3] * inv));
}

// attn[h][s][t] = bf2f(expS) * invRow -- pure streaming, grid-stride.
// Each thread handles 16 contiguous elems: 32B bf16 read -> 64B fp32 write.
__global__ void attn_norm(const u16* __restrict__ expS,
                          const float* __restrict__ invRow,
                          float* __restrict__ attn) {
  const long TOT = ((long)NHEAD << 24) >> 4;  // chunks of 16
  long c = (long)blockIdx.x * 256 + threadIdx.x;
  const long stride = (long)gridDim.x * 256;
  for (; c < TOT; c += stride) {
    long flat = c << 4;
    float inv = invRow[flat >> 12];  // (h<<24 + s*4096 + t) >> 12 == h*4096+s
    u16x8 v0 = __builtin_nontemporal_load((const u16x8*)(expS + flat));
    u16x8 v1 = __builtin_nontemporal_load((const u16x8*)(expS + flat + 8));
    f32x4 w0 = {bf2f(v0[0]) * inv, bf2f(v0[1]) * inv, bf2f(v0[2]) * inv, bf2f(v0[3]) * inv};
    f32x4 w1 = {bf2f(v0[4]) * inv, bf2f(v0[5]) * inv, bf2f(v0[6]) * inv, bf2f(v0[7]) * inv};
    f32x4 w2 = {bf2f(v1[0]) * inv, bf2f(v1[1]) * inv, bf2f(v1[2]) * inv, bf2f(v1[3]) * inv};
    f32x4 w3 = {bf2f(v1[4]) * inv, bf2f(v1[5]) * inv, bf2f(v1[6]) * inv, bf2f(v1[7]) * inv};
    __builtin_nontemporal_store(w0, (f32x4*)(attn + flat));
    __builtin_nontemporal_store(w1, (f32x4*)(attn + flat + 4));
    __builtin_nontemporal_store(w2, (f32x4*)(attn + flat + 8));
    __builtin_nontemporal_store(w3, (f32x4*)(attn + flat + 12));
  }
}

// ---------------------------------------------------------------- fallback (fp32-in-attn) PV
// Only used when ws can't hold bf16 expS. Unchanged fused normalize+PV.
template <bool BF16S>
__global__ __launch_bounds__(256, 2) void pv_norm(
    const void* __restrict__ expS, const float* __restrict__ invRow,
    float* __restrict__ attnOut, const u16* __restrict__ Vt,
    u16* __restrict__ Yb) {
  __shared__ u16 sP[64 * 64];   // 8 KB
  __shared__ u16 sV[128 * 64];  // 16 KB
  const int tid = threadIdx.x;
  const int lane = tid & 63, wave = tid >> 6;
  const int wr = wave >> 1, wc = wave & 1;
  const int quad = lane >> 4, l16 = lane & 15;
  const int h = blockIdx.z;
  const int bm = blockIdx.y * 64;

  f32x4 acc[2][4];
#pragma unroll
  for (int i = 0; i < 2; i++)
#pragma unroll
    for (int j = 0; j < 4; j++) acc[i][j] = (f32x4)0.0f;

  for (int k0 = 0; k0 < SEQ; k0 += 64) {
#pragma unroll
    for (int c = 0; c < 2; ++c) {
      int e = (c * 256 + tid) * 8;
      int row = e >> 6, col = e & 63;
      long arow = (long)h * SEQ + bm + row;
      long g = arow * SEQ + k0 + col;
      float inv = invRow[arow];
      float p[8];
      if constexpr (BF16S) {
        ushort4 u0 = *(const ushort4*)((const u16*)expS + g);
        ushort4 u1 = *(const ushort4*)((const u16*)expS + g + 4);
        p[0] = bf2f(u0.x) * inv; p[1] = bf2f(u0.y) * inv;
        p[2] = bf2f(u0.z) * inv; p[3] = bf2f(u0.w) * inv;
        p[4] = bf2f(u1.x) * inv; p[5] = bf2f(u1.y) * inv;
        p[6] = bf2f(u1.z) * inv; p[7] = bf2f(u1.w) * inv;
      } else {
        float4 f0 = *(const float4*)((const float*)expS + g);
        float4 f1 = *(const float4*)((const float*)expS + g + 4);
        p[0] = f0.x * inv; p[1] = f0.y * inv; p[2] = f0.z * inv; p[3] = f0.w * inv;
        p[4] = f1.x * inv; p[5] = f1.y * inv; p[6] = f1.z * inv; p[7] = f1.w * inv;
      }
      *(float4*)(attnOut + g) = make_float4(p[0], p[1], p[2], p[3]);
      *(float4*)(attnOut + g + 4) = make_float4(p[4], p[5], p[6], p[7]);
      *(ushort4*)(sP + e) = make_ushort4(f2bf(p[0]), f2bf(p[1]), f2bf(p[2]), f2bf(p[3]));
      *(ushort4*)(sP + e + 4) = make_ushort4(f2bf(p[4]), f2bf(p[5]), f2bf(p[6]), f2bf(p[7]));
    }
#pragma unroll
    for (int r = 0; r < 4; ++r) {
      int e = (r * 256 + tid) * 8;
      int row = e >> 6, col = e & 63;
      g2l16(Vt + (long)(h * DK + row) * SEQ + k0 + col, (char*)sV + (size_t)e * 2);
    }
    __syncthreads();
#pragma unroll
    for (int ks = 0; ks < 64; ks += 32) {
      bf16x8 a[2], b[4];
#pragma unroll
      for (int i = 0; i < 2; i++)
        a[i] = *(const bf16x8*)&sP[(wr * 32 + i * 16 + l16) * 64 + ks + quad * 8];
#pragma unroll
      for (int i = 0; i < 4; i++)
        b[i] = *(const bf16x8*)&sV[(wc * 64 + i * 16 + l16) * 64 + ks + quad * 8];
#pragma unroll
      for (int mi = 0; mi < 2; mi++)
#pragma unroll
        for (int ni = 0; ni < 4; ni++)
          acc[mi][ni] = __builtin_amdgcn_mfma_f32_16x16x32_bf16(a[mi], b[ni], acc[mi][ni], 0, 0, 0);
    }
    __syncthreads();
  }

#pragma unroll
  for (int mi = 0; mi < 2; mi++)
#pragma unroll
    for (int ni = 0; ni < 4; ni++)
#pragma unroll
      for (int r = 0; r < 4; r++) {
        long row = bm + wr * 32 + mi * 16 + quad * 4 + r;
        int col = h * DK + wc * 64 + ni * 16 + l16;
        Yb[row * (long)FDIM + col] = f2bf(acc[mi][ni][r]);
      }
}

// ---------------------------------------------------------------- launcher

extern "C" void kernel_launch(void* const* d_in, const int* in_sizes, int n_in,
                              void* d_out, int out_size, void* d_ws, size_t ws_size,
                              hipStream_t stream) {
  const float* x = (const float*)d_in[0];
  const float* Wq = (const float*)d_in[1];
  const float* Wk = (const float*)d_in[2];
  const float* Wv = (const float*)d_in[3];
  const float* Wo = (const float*)d_in[4];

  float* outY = (float*)d_out;              // 4096*1024
  float* attn = outY + (size_t)SEQ * FDIM;  // 8*4096*4096

  const size_t NX = (size_t)SEQ * FDIM;   // 4194304
  const size_t NW = (size_t)FDIM * FDIM;  // 1048576

  u16* p = (u16*)d_ws;
  u16* xhi = p; p += NX;
  u16* xlo = p; p += NX;
  u16* wqt_h = p; p += NW;
  u16* wqt_l = p; p += NW;
  u16* wkt_h = p; p += NW;   // wqt_h + 2*NW (z-stride for fused QK proj)
  u16* wkt_l = p; p += NW;
  u16* wvt = p; p += NW;
  u16* wot = p; p += NW;
  u16* Qhi = p; p += NX;
  u16* Qlo = p; p += NX;
  u16* Khi = p; p += NX;     // Qhi + 2*NX
  u16* Klo = p; p += NX;
  u16* Vb = p; p += NX;
  u16* Vt = p; p += NX;
  u16* Yb = p; p += NX;
  float* rowSum = (float*)p;
  float* invRow = rowSum + (size_t)NHEAD * SEQ;
  u16* expS = (u16*)(invRow + (size_t)NHEAD * SEQ);
  size_t need = (size_t)((char*)(expS + (size_t)NHEAD * SEQ * SEQ) - (char*)d_ws);
  bool bf16s = ws_size >= need;

  hipMemsetAsync(rowSum, 0, (size_t)NHEAD * SEQ * sizeof(float), stream);

  split_f32_bf16<<<dim3((NX / 4 + 255) / 256), 256, 0, stream>>>(
      (const float4*)x, xhi, xlo, NX / 4);

  dim3 tb(32, 8);
  transpose_split_w<<<dim3(32, 32), tb, 0, stream>>>(Wq, wqt_h, wqt_l, FDIM, 1);
  transpose_split_w<<<dim3(32, 32), tb, 0, stream>>>(Wk, wkt_h, wkt_l, FDIM, 1);
  transpose_split_w<<<dim3(32, 32), tb, 0, stream>>>(Wv, wvt, nullptr, FDIM, 0);
  transpose_split_w<<<dim3(32, 32), tb, 0, stream>>>(Wo, wot, nullptr, FDIM, 0);

  // Q and K projections fused (z=0 -> Q, z=1 -> K), split in/out
  gemm_bt<32, true, 2><<<dim3(8, 32, 2), 256, 0, stream>>>(
      xhi, xlo, wqt_h, wqt_l, Qhi, Qlo,
      1024, 1024, 1024, 1024, 0, (long)2 * NW, (long)2 * NX);

  // V projection (plain bf16) + transpose
  gemm_bt<64, false, 1><<<dim3(8, 32, 1), 256, 0, stream>>>(
      xhi, nullptr, wvt, nullptr, Vb, nullptr,
      1024, 1024, 1024, 1024, 0, 0, 0);
  transpose_bf16<<<dim3(32, 128), tb, 0, stream>>>(Vb, Vt, SEQ, FDIM);

  const float scale = 0.08838834764831845f;  // 1/sqrt(128)
  if (bf16s) {
    qk_exp<true><<<dim3(32, 32, NHEAD), 256, 0, stream>>>(
        Qhi, Qlo, Khi, Klo, expS, rowSum, scale);
    reciprocal_k<<<(NHEAD * SEQ + 255) / 256, 256, 0, stream>>>(rowSum, invRow, NHEAD * SEQ);

    // y_un partials go into the attn output region (scratch until attn_norm).
    float* ypart = attn;
    pv_gemm<<<dim3(KSPLIT, 32, NHEAD), 256, 0, stream>>>(expS, Vt, ypart);
    y_reduce_scale<<<dim3(NX / 4 / 256), 256, 0, stream>>>(ypart, invRow, Yb);
    attn_norm<<<dim3(2048), 256, 0, stream>>>(expS, invRow, attn);
  } else {
    qk_exp<false><<<dim3(32, 32, NHEAD), 256, 0, stream>>>(
        Qhi, Qlo, Khi, Klo, attn, rowSum, scale);
    reciprocal_k<<<(NHEAD * SEQ + 255) / 256, 256, 0, stream>>>(rowSum, invRow, NHEAD * SEQ);
    pv_norm<false><<<dim3(1, 64, NHEAD), 256, 0, stream>>>(attn, invRow, attn, Vt, Yb);
  }

  // out = y @ Wo
  gemm_bt<64, false, 0><<<dim3(8, 32, 1), 256, 0, stream>>>(
      Yb, nullptr, wot, nullptr, outY, nullptr,
      1024, 1024, 1024, 1024, 0, 0, 0);
}

// Round 5
// 1020.281 us; speedup vs baseline: 1.2444x; 1.2444x over previous
//
#include <hip/hip_runtime.h>
#include <math.h>

// MultiHeadAttention: x[1,4096,1024] fp32, Wq/Wk/Wv[1024,1024], Wo[1024,1024].
// Outputs (concat in d_out): y[4096*1024] fp32, attn[8*4096*4096] fp32.
//
// R5 structure (recompute, no expS scratch):
//   split x / transpose weights -> Q,K proj (split-bf16, fused z=2 launch),
//   V proj + transpose ->
//   qk_rowsum (split QK, exp, rowsums only -- NO S store) ->
//   reciprocal ->
//   attn_pv   (flash-style: recompute S per tile with the bit-identical
//              3-MFMA split sequence, normalize, write attn fp32 directly,
//              and accumulate y = P@V in-loop; K staged via pre-swizzled
//              global_load_lds, V frags direct from L2, head-per-XCD grid) ->
//   Wo proj.
// Rationale (R3/R4 counters): the expS round-trip (268 MB write + read +
// dirty-writeback churn) cost ~250+ us at the observed ~2.7-3.8 TB/s
// write-heavy wall; recomputing QK^T costs ~+100 us of MFMA and removes all
// of it. Plain stores everywhere (nontemporal measurably hurt: 2.7 vs 3.8).

typedef unsigned short u16;
typedef __attribute__((ext_vector_type(8))) short bf16x8;
typedef __attribute__((ext_vector_type(8))) unsigned short u16x8;
typedef __attribute__((ext_vector_type(4))) float f32x4;

#define SEQ 4096
#define FDIM 1024
#define NHEAD 8
#define DK 128

__device__ __forceinline__ u16 f2bf(float f) {
  unsigned u = __float_as_uint(f);
  u += 0x7fffu + ((u >> 16) & 1u);  // round-to-nearest-even
  return (u16)(u >> 16);
}
__device__ __forceinline__ float bf2f(u16 h) {
  return __uint_as_float(((unsigned)h) << 16);
}

__device__ __forceinline__ void g2l16(const void* g, void* l) {
  __builtin_amdgcn_global_load_lds(
      (const __attribute__((address_space(1))) void*)g,
      (__attribute__((address_space(3))) void*)l, 16, 0, 0);
}

// ---------------------------------------------------------------- prep kernels

__global__ void split_f32_bf16(const float4* __restrict__ in, u16* __restrict__ ohi,
                               u16* __restrict__ olo, int n4) {
  int i = blockIdx.x * 256 + threadIdx.x;
  if (i >= n4) return;
  float4 v = in[i];
  u16 h0 = f2bf(v.x), h1 = f2bf(v.y), h2 = f2bf(v.z), h3 = f2bf(v.w);
  u16 l0 = f2bf(v.x - bf2f(h0)), l1 = f2bf(v.y - bf2f(h1));
  u16 l2 = f2bf(v.z - bf2f(h2)), l3 = f2bf(v.w - bf2f(h3));
  *(ushort4*)(ohi + 4 * (size_t)i) = make_ushort4(h0, h1, h2, h3);
  *(ushort4*)(olo + 4 * (size_t)i) = make_ushort4(l0, l1, l2, l3);
}

// out[n][k] = in[k][n], 1024x1024, optional split
__global__ void transpose_split_w(const float* __restrict__ in, u16* __restrict__ ohi,
                                  u16* __restrict__ olo, int dim, int do_split) {
  __shared__ float t[32][33];
  int tx = threadIdx.x, ty = threadIdx.y;
  int x = blockIdx.x * 32 + tx;
  int y0 = blockIdx.y * 32;
  for (int j = ty; j < 32; j += 8) t[j][tx] = in[(long)(y0 + j) * dim + x];
  __syncthreads();
  int x2 = y0 + tx;
  int y2 = blockIdx.x * 32;
  for (int j = ty; j < 32; j += 8) {
    float v = t[tx][j];
    u16 hi = f2bf(v);
    ohi[(long)(y2 + j) * dim + x2] = hi;
    if (do_split) olo[(long)(y2 + j) * dim + x2] = f2bf(v - bf2f(hi));
  }
}

__global__ void transpose_bf16(const u16* __restrict__ in, u16* __restrict__ out,
                               int rows, int cols) {
  __shared__ u16 t[32][33];
  int tx = threadIdx.x, ty = threadIdx.y;
  int x = blockIdx.x * 32 + tx;
  int y0 = blockIdx.y * 32;
  for (int j = ty; j < 32; j += 8) t[j][tx] = in[(long)(y0 + j) * cols + x];
  __syncthreads();
  int x2 = y0 + tx;
  int y2 = blockIdx.x * 32;
  for (int j = ty; j < 32; j += 8) out[(long)(y2 + j) * rows + x2] = t[tx][j];
}

__global__ void reciprocal_k(const float* __restrict__ in, float* __restrict__ out, int n) {
  int i = blockIdx.x * 256 + threadIdx.x;
  if (i < n) out[i] = 1.0f / in[i];
}

// ---------------------------------------------------------------- projection GEMM (C = A * B^T)
// EPI: 0 = fp32 store, 1 = bf16 store, 2 = split bf16 store
template <int BK, bool SPLIT, int EPI>
__global__ __launch_bounds__(256, 2) void gemm_bt(
    const u16* Ahi_, const u16* Alo_,
    const u16* Bhi_, const u16* Blo_,
    void* C0, void* C1,
    int Kdim, int lda, int ldb, int ldc,
    long aStrH, long bStrH, long cStrH) {
  constexpr int LDSN = 128 * BK;
  __shared__ u16 sAhi[LDSN];
  __shared__ u16 sBhi[LDSN];
  __shared__ u16 sAlo[SPLIT ? LDSN : 2];
  __shared__ u16 sBlo[SPLIT ? LDSN : 2];

  const int tid = threadIdx.x;
  const int lane = tid & 63;
  const int wave = tid >> 6;
  const int wr = wave >> 1, wc = wave & 1;
  const int quad = lane >> 4, l16 = lane & 15;
  const int h = blockIdx.z;
  const long bm = (long)blockIdx.y * 128;
  const long bn = (long)blockIdx.x * 128;

  const u16* Ahi = Ahi_ + (long)h * aStrH;
  const u16* Alo = SPLIT ? (Alo_ + (long)h * aStrH) : nullptr;
  const u16* Bhi = Bhi_ + (long)h * bStrH;
  const u16* Blo = SPLIT ? (Blo_ + (long)h * bStrH) : nullptr;

  f32x4 acc[4][4];
#pragma unroll
  for (int i = 0; i < 4; i++)
#pragma unroll
    for (int j = 0; j < 4; j++) acc[i][j] = (f32x4)0.0f;

  for (int k0 = 0; k0 < Kdim; k0 += BK) {
    constexpr int GR = (128 * BK) / (256 * 8);
#pragma unroll
    for (int r = 0; r < GR; ++r) {
      int e = (r * 256 + tid) * 8;
      int row = e / BK, col = e % BK;
      long ga = (bm + row) * (long)lda + k0 + col;
      long gb = (bn + row) * (long)ldb + k0 + col;
      g2l16(Ahi + ga, (char*)sAhi + (size_t)e * 2);
      g2l16(Bhi + gb, (char*)sBhi + (size_t)e * 2);
      if constexpr (SPLIT) {
        g2l16(Alo + ga, (char*)sAlo + (size_t)e * 2);
        g2l16(Blo + gb, (char*)sBlo + (size_t)e * 2);
      }
    }
    __syncthreads();

#pragma unroll
    for (int ks = 0; ks < BK; ks += 32) {
      bf16x8 aH[4], bH[4];
      bf16x8 aL[SPLIT ? 4 : 1], bL[SPLIT ? 4 : 1];
#pragma unroll
      for (int mi = 0; mi < 4; mi++) {
        int off = (wr * 64 + mi * 16 + l16) * BK + ks + quad * 8;
        aH[mi] = *(const bf16x8*)&sAhi[off];
        if constexpr (SPLIT) aL[mi] = *(const bf16x8*)&sAlo[off];
      }
#pragma unroll
      for (int ni = 0; ni < 4; ni++) {
        int off = (wc * 64 + ni * 16 + l16) * BK + ks + quad * 8;
        bH[ni] = *(const bf16x8*)&sBhi[off];
        if constexpr (SPLIT) bL[ni] = *(const bf16x8*)&sBlo[off];
      }
#pragma unroll
      for (int mi = 0; mi < 4; mi++)
#pragma unroll
        for (int ni = 0; ni < 4; ni++) {
          acc[mi][ni] = __builtin_amdgcn_mfma_f32_16x16x32_bf16(aH[mi], bH[ni], acc[mi][ni], 0, 0, 0);
          if constexpr (SPLIT) {
            acc[mi][ni] = __builtin_amdgcn_mfma_f32_16x16x32_bf16(aH[mi], bL[ni], acc[mi][ni], 0, 0, 0);
            acc[mi][ni] = __builtin_amdgcn_mfma_f32_16x16x32_bf16(aL[mi], bH[ni], acc[mi][ni], 0, 0, 0);
          }
        }
    }
    __syncthreads();
  }

  const long rowB = bm + wr * 64;
  const long colB = bn + wc * 64;
  if constexpr (EPI == 2) {
    u16* Chi = (u16*)C0 + (long)h * cStrH;
    u16* Clo = (u16*)C1 + (long)h * cStrH;
#pragma unroll
    for (int mi = 0; mi < 4; mi++)
#pragma unroll
      for (int ni = 0; ni < 4; ni++) {
        long col = colB + ni * 16 + l16;
#pragma unroll
        for (int r = 0; r < 4; r++) {
          long idx = (rowB + mi * 16 + quad * 4 + r) * (long)ldc + col;
          float v = acc[mi][ni][r];
          u16 hi = f2bf(v);
          Chi[idx] = hi;
          Clo[idx] = f2bf(v - bf2f(hi));
        }
      }
  } else if constexpr (EPI == 1) {
    u16* C = (u16*)C0 + (long)h * cStrH;
#pragma unroll
    for (int mi = 0; mi < 4; mi++)
#pragma unroll
      for (int ni = 0; ni < 4; ni++) {
        long col = colB + ni * 16 + l16;
#pragma unroll
        for (int r = 0; r < 4; r++)
          C[(rowB + mi * 16 + quad * 4 + r) * (long)ldc + col] = f2bf(acc[mi][ni][r]);
      }
  } else {
    float* C = (float*)C0 + (long)h * cStrH;
#pragma unroll
    for (int mi = 0; mi < 4; mi++)
#pragma unroll
      for (int ni = 0; ni < 4; ni++) {
        long col = colB + ni * 16 + l16;
#pragma unroll
        for (int r = 0; r < 4; r++)
          C[(rowB + mi * 16 + quad * 4 + r) * (long)ldc + col] = acc[mi][ni][r];
      }
  }
}

// ---------------------------------------------------------------- pass 1: QK^T rowsums
// rowSum[h][s] += sum_t exp(scale * (Q K^T)[s][t]); NO S store.
// Identical split-MFMA accumulation sequence as attn_pv so exp values match
// bit-for-bit between passes.
__global__ __launch_bounds__(256, 2) void qk_rowsum(
    const u16* __restrict__ Qhi, const u16* __restrict__ Qlo,
    const u16* __restrict__ Khi, const u16* __restrict__ Klo,
    float* __restrict__ rowSum, float scale) {
  __shared__ u16 smem[32768];  // 64 KB staging
  u16* sQh = smem;
  u16* sQl = smem + 8192;
  u16* sKh = smem + 16384;
  u16* sKl = smem + 24576;

  const int tid = threadIdx.x;
  const int lane = tid & 63, wave = tid >> 6;
  const int wr = wave >> 1, wc = wave & 1;
  const int quad = lane >> 4, l16 = lane & 15;
  const int h = blockIdx.z;
  const int bm = blockIdx.y * 128, bn = blockIdx.x * 128;
  const int colOff = h * DK;

  f32x4 acc[4][4];
#pragma unroll
  for (int i = 0; i < 4; i++)
#pragma unroll
    for (int j = 0; j < 4; j++) acc[i][j] = (f32x4)0.0f;

  for (int k0 = 0; k0 < DK; k0 += 64) {
#pragma unroll
    for (int r = 0; r < 4; ++r) {
      int e = (r * 256 + tid) * 8;
      int row = e >> 6, col = e & 63;
      long gq = (long)(bm + row) * FDIM + colOff + k0 + col;
      long gk = (long)(bn + row) * FDIM + colOff + k0 + col;
      g2l16(Qhi + gq, (char*)sQh + (size_t)e * 2);
      g2l16(Qlo + gq, (char*)sQl + (size_t)e * 2);
      g2l16(Khi + gk, (char*)sKh + (size_t)e * 2);
      g2l16(Klo + gk, (char*)sKl + (size_t)e * 2);
    }
    __syncthreads();
#pragma unroll
    for (int ks = 0; ks < 64; ks += 32) {
      bf16x8 aH[4], aL[4], bH[4], bL[4];
#pragma unroll
      for (int i = 0; i < 4; i++) {
        int offA = (wr * 64 + i * 16 + l16) * 64 + ks + quad * 8;
        int offB = (wc * 64 + i * 16 + l16) * 64 + ks + quad * 8;
        aH[i] = *(const bf16x8*)&sQh[offA];
        aL[i] = *(const bf16x8*)&sQl[offA];
        bH[i] = *(const bf16x8*)&sKh[offB];
        bL[i] = *(const bf16x8*)&sKl[offB];
      }
#pragma unroll
      for (int mi = 0; mi < 4; mi++)
#pragma unroll
        for (int ni = 0; ni < 4; ni++) {
          acc[mi][ni] = __builtin_amdgcn_mfma_f32_16x16x32_bf16(aH[mi], bH[ni], acc[mi][ni], 0, 0, 0);
          acc[mi][ni] = __builtin_amdgcn_mfma_f32_16x16x32_bf16(aH[mi], bL[ni], acc[mi][ni], 0, 0, 0);
          acc[mi][ni] = __builtin_amdgcn_mfma_f32_16x16x32_bf16(aL[mi], bH[ni], acc[mi][ni], 0, 0, 0);
        }
    }
    __syncthreads();
  }

  // exp + per-row sums (shfl over the 16 col-lanes, atomic per block)
#pragma unroll
  for (int mi = 0; mi < 4; mi++) {
    f32x4 rs = (f32x4)0.0f;
#pragma unroll
    for (int ni = 0; ni < 4; ni++)
#pragma unroll
      for (int r = 0; r < 4; r++) rs[r] += __expf(acc[mi][ni][r] * scale);
#pragma unroll
    for (int m = 1; m < 16; m <<= 1) {
      rs[0] += __shfl_xor(rs[0], m);
      rs[1] += __shfl_xor(rs[1], m);
      rs[2] += __shfl_xor(rs[2], m);
      rs[3] += __shfl_xor(rs[3], m);
    }
    if (l16 == 0) {
      int rbase = h * SEQ + bm + wr * 64 + mi * 16 + quad * 4;
#pragma unroll
      for (int r = 0; r < 4; r++) atomicAdd(&rowSum[rbase + r], rs[r]);
    }
  }
}

// ---------------------------------------------------------------- pass 2: fused attn + PV
// Per block: 64-row panel of head h. Sweep 64-col K-panels: recompute S
// (split, bit-identical to pass 1), P = exp(S*scale)*invRow -> swizzled sP
// (bf16); write attn fp32 from sP (coalesced); y += P @ V via MFMA with V
// fragments loaded direct from global (L2-resident; head-per-XCD grid).
// LDS: K double-buffered 64 KB + sP 8 KB = 72 KB -> 2 blocks/CU.
// Swizzle: 16B-chunk XOR with (row&7) kills the 16-way ds_read_b128 bank
// conflicts of a 256B/128B-stride row-major tile (guide G4/T2); K staging
// keeps LDS linear and pre-swizzles the GLOBAL source (rule #21).
__global__ __launch_bounds__(256, 2) void attn_pv(
    const u16* __restrict__ Qhi, const u16* __restrict__ Qlo,
    const u16* __restrict__ Khi, const u16* __restrict__ Klo,
    const u16* __restrict__ Vt, const float* __restrict__ invRow,
    float* __restrict__ attn, u16* __restrict__ Yb, float scale) {
  __shared__ u16 sKh[2][8192];  // [64 rows][128 dk] bf16, swizzled; x2 dbuf
  __shared__ u16 sKl[2][8192];
  __shared__ u16 sP[4096];      // [64][64] bf16, swizzled

  const int tid = threadIdx.x;
  const int lane = tid & 63, wave = tid >> 6;
  const int wr = wave >> 1, wc = wave & 1;
  const int quad = lane >> 4, l16 = lane & 15;
  const int h = blockIdx.x;   // head on blockIdx.x -> linear id % 8 == h -> head-per-XCD
  const int bm = blockIdx.y * 64;
  const int colOff = h * DK;

  // Q fragments in registers (loaded once): A-frag row = bm+wr*32+mi*16+l16,
  // k-chunk = kk*32 + quad*8.  16 x bf16x8 = 64 VGPR.
  bf16x8 qH[2][4], qL[2][4];
#pragma unroll
  for (int mi = 0; mi < 2; mi++)
#pragma unroll
    for (int kk = 0; kk < 4; kk++) {
      long g = (long)(bm + wr * 32 + mi * 16 + l16) * FDIM + colOff + kk * 32 + quad * 8;
      qH[mi][kk] = *(const bf16x8*)(Qhi + g);
      qL[mi][kk] = *(const bf16x8*)(Qlo + g);
    }

  // per-thread normalizers for the 8 S-rows this thread produces
  float invr[2][4];
#pragma unroll
  for (int mi = 0; mi < 2; mi++)
#pragma unroll
    for (int rr = 0; rr < 4; rr++)
      invr[mi][rr] = invRow[(long)h * SEQ + bm + wr * 32 + mi * 16 + quad * 4 + rr];

  f32x4 yacc[2][4];
#pragma unroll
  for (int i = 0; i < 2; i++)
#pragma unroll
    for (int j = 0; j < 4; j++) yacc[i][j] = (f32x4)0.0f;

  const long attnRowBase = ((long)h * SEQ + bm) * (long)SEQ;

  // stage K panel bn -> buf: linear LDS dest, pre-swizzled global source.
  // physical 16B chunk c: row = c>>4, logical col-chunk = (c&15) ^ (row&7).
  auto STAGEK = [&](int bn, int buf) {
#pragma unroll
    for (int r = 0; r < 4; ++r) {
      int c = r * 256 + tid;
      int row = c >> 4;
      int jl = (c & 15) ^ (row & 7);
      long g = (long)(bn + row) * FDIM + colOff + jl * 8;
      g2l16(Khi + g, (char*)sKh[buf] + (size_t)c * 16);
      g2l16(Klo + g, (char*)sKl[buf] + (size_t)c * 16);
    }
  };

  STAGEK(0, 0);
  __syncthreads();

  int cur = 0;
  for (int it = 0; it < 64; ++it) {
    const int bn = it * 64;
    if (it < 63) STAGEK(bn + 64, cur ^ 1);  // async issue; drains at mid barrier

    // V fragments for this panel, direct from global (L2): B-frag row =
    // dk index (y col), k = bn offset.  Issued early to hide under QK MFMA.
    bf16x8 vfr[4][2];
#pragma unroll
    for (int ni = 0; ni < 4; ni++)
#pragma unroll
      for (int ks = 0; ks < 2; ks++)
        vfr[ni][ks] = *(const bf16x8*)(
            Vt + (long)(colOff + wc * 64 + ni * 16 + l16) * SEQ + bn + ks * 32 + quad * 8);

    // ---- QK^T (split hi/lo, 3 MFMA; same k-chunk order as qk_rowsum)
    f32x4 sacc[2][2];
#pragma unroll
    for (int i = 0; i < 2; i++) {
      sacc[i][0] = (f32x4)0.0f;
      sacc[i][1] = (f32x4)0.0f;
    }
#pragma unroll
    for (int kk = 0; kk < 4; kk++) {
      bf16x8 bH[2], bL[2];
#pragma unroll
      for (int ni = 0; ni < 2; ni++) {
        int krow = wc * 32 + ni * 16 + l16;
        int byo = (krow * 256 + kk * 64 + quad * 16) ^ ((krow & 7) << 4);
        bH[ni] = *(const bf16x8*)((const char*)sKh[cur] + byo);
        bL[ni] = *(const bf16x8*)((const char*)sKl[cur] + byo);
      }
#pragma unroll
      for (int mi = 0; mi < 2; mi++)
#pragma unroll
        for (int ni = 0; ni < 2; ni++) {
          sacc[mi][ni] = __builtin_amdgcn_mfma_f32_16x16x32_bf16(qH[mi][kk], bH[ni], sacc[mi][ni], 0, 0, 0);
          sacc[mi][ni] = __builtin_amdgcn_mfma_f32_16x16x32_bf16(qH[mi][kk], bL[ni], sacc[mi][ni], 0, 0, 0);
          sacc[mi][ni] = __builtin_amdgcn_mfma_f32_16x16x32_bf16(qL[mi][kk], bH[ni], sacc[mi][ni], 0, 0, 0);
        }
    }

    // ---- P = exp(S*scale) * invRow -> sP (swizzled bf16)
#pragma unroll
    for (int mi = 0; mi < 2; mi++)
#pragma unroll
      for (int ni = 0; ni < 2; ni++)
#pragma unroll
        for (int rr = 0; rr < 4; rr++) {
          int prow = wr * 32 + mi * 16 + quad * 4 + rr;
          int pcol = wc * 32 + ni * 16 + l16;
          float pv = __expf(sacc[mi][ni][rr] * scale) * invr[mi][rr];
          int byo = (prow * 128 + pcol * 2) ^ ((prow & 7) << 4);
          *(u16*)((char*)sP + byo) = f2bf(pv);
        }
    __syncthreads();  // sP visible; also drains next-panel K stage

    // ---- y += P @ V
#pragma unroll
    for (int ks = 0; ks < 2; ks++) {
      bf16x8 a[2];
#pragma unroll
      for (int mi = 0; mi < 2; mi++) {
        int prow = wr * 32 + mi * 16 + l16;
        int byo = (prow * 128 + ks * 64 + quad * 16) ^ ((prow & 7) << 4);
        a[mi] = *(const bf16x8*)((const char*)sP + byo);
      }
#pragma unroll
      for (int mi = 0; mi < 2; mi++)
#pragma unroll
        for (int ni = 0; ni < 4; ni++)
          yacc[mi][ni] = __builtin_amdgcn_mfma_f32_16x16x32_bf16(a[mi], vfr[ni][ks], yacc[mi][ni], 0, 0, 0);
    }

    // ---- attn tile store (fp32, coalesced, from sP)
#pragma unroll
    for (int half = 0; half < 2; ++half) {
      int e = half * 2048 + tid * 8;
      int r = e >> 6, c8 = e & 63;
      int byo = (r * 128 + c8 * 2) ^ ((r & 7) << 4);
      u16x8 u = *(const u16x8*)((const char*)sP + byo);
      long g = attnRowBase + (long)r * SEQ + bn + c8;
      *(float4*)(attn + g) = make_float4(bf2f(u[0]), bf2f(u[1]), bf2f(u[2]), bf2f(u[3]));
      *(float4*)(attn + g + 4) = make_float4(bf2f(u[4]), bf2f(u[5]), bf2f(u[6]), bf2f(u[7]));
    }
    __syncthreads();  // protect sP and K buf before next iteration overwrites
    cur ^= 1;
  }

  // ---- y epilogue (bf16 Yb for the Wo GEMM)
#pragma unroll
  for (int mi = 0; mi < 2; mi++)
#pragma unroll
    for (int ni = 0; ni < 4; ni++)
#pragma unroll
      for (int r = 0; r < 4; r++) {
        long row = bm + wr * 32 + mi * 16 + quad * 4 + r;
        int col = colOff + wc * 64 + ni * 16 + l16;
        Yb[row * (long)FDIM + col] = f2bf(yacc[mi][ni][r]);
      }
}

// ---------------------------------------------------------------- launcher

extern "C" void kernel_launch(void* const* d_in, const int* in_sizes, int n_in,
                              void* d_out, int out_size, void* d_ws, size_t ws_size,
                              hipStream_t stream) {
  const float* x = (const float*)d_in[0];
  const float* Wq = (const float*)d_in[1];
  const float* Wk = (const float*)d_in[2];
  const float* Wv = (const float*)d_in[3];
  const float* Wo = (const float*)d_in[4];

  float* outY = (float*)d_out;              // 4096*1024
  float* attn = outY + (size_t)SEQ * FDIM;  // 8*4096*4096

  const size_t NX = (size_t)SEQ * FDIM;   // 4194304
  const size_t NW = (size_t)FDIM * FDIM;  // 1048576

  u16* p = (u16*)d_ws;
  u16* xhi = p; p += NX;
  u16* xlo = p; p += NX;
  u16* wqt_h = p; p += NW;
  u16* wqt_l = p; p += NW;
  u16* wkt_h = p; p += NW;   // wqt_h + 2*NW (z-stride for fused QK proj)
  u16* wkt_l = p; p += NW;
  u16* wvt = p; p += NW;
  u16* wot = p; p += NW;
  u16* Qhi = p; p += NX;
  u16* Qlo = p; p += NX;
  u16* Khi = p; p += NX;     // Qhi + 2*NX
  u16* Klo = p; p += NX;
  u16* Vb = p; p += NX;
  u16* Vt = p; p += NX;
  u16* Yb = p; p += NX;
  float* rowSum = (float*)p;
  float* invRow = rowSum + (size_t)NHEAD * SEQ;

  hipMemsetAsync(rowSum, 0, (size_t)NHEAD * SEQ * sizeof(float), stream);

  split_f32_bf16<<<dim3((NX / 4 + 255) / 256), 256, 0, stream>>>(
      (const float4*)x, xhi, xlo, NX / 4);

  dim3 tb(32, 8);
  transpose_split_w<<<dim3(32, 32), tb, 0, stream>>>(Wq, wqt_h, wqt_l, FDIM, 1);
  transpose_split_w<<<dim3(32, 32), tb, 0, stream>>>(Wk, wkt_h, wkt_l, FDIM, 1);
  transpose_split_w<<<dim3(32, 32), tb, 0, stream>>>(Wv, wvt, nullptr, FDIM, 0);
  transpose_split_w<<<dim3(32, 32), tb, 0, stream>>>(Wo, wot, nullptr, FDIM, 0);

  // Q and K projections fused (z=0 -> Q, z=1 -> K), split in/out
  gemm_bt<32, true, 2><<<dim3(8, 32, 2), 256, 0, stream>>>(
      xhi, xlo, wqt_h, wqt_l, Qhi, Qlo,
      1024, 1024, 1024, 1024, 0, (long)2 * NW, (long)2 * NX);

  // V projection (plain bf16) + transpose
  gemm_bt<64, false, 1><<<dim3(8, 32, 1), 256, 0, stream>>>(
      xhi, nullptr, wvt, nullptr, Vb, nullptr,
      1024, 1024, 1024, 1024, 0, 0, 0);
  transpose_bf16<<<dim3(32, 128), tb, 0, stream>>>(Vb, Vt, SEQ, FDIM);

  const float scale = 0.08838834764831845f;  // 1/sqrt(128)

  // pass 1: rowsums only (no S store)
  qk_rowsum<<<dim3(32, 32, NHEAD), 256, 0, stream>>>(
      Qhi, Qlo, Khi, Klo, rowSum, scale);

  reciprocal_k<<<(NHEAD * SEQ + 255) / 256, 256, 0, stream>>>(rowSum, invRow, NHEAD * SEQ);

  // pass 2: recompute S, write attn, accumulate y = P @ V
  attn_pv<<<dim3(NHEAD, 64, 1), 256, 0, stream>>>(
      Qhi, Qlo, Khi, Klo, Vt, invRow, attn, Yb, scale);

  // out = y @ Wo
  gemm_bt<64, false, 0><<<dim3(8, 32, 1), 256, 0, stream>>>(
      Yb, nullptr, wot, nullptr, outY, nullptr,
      1024, 1024, 1024, 1024, 0, 0, 0);
}

// Round 7
// 1015.707 us; speedup vs baseline: 1.2500x; 1.0045x over previous
//
#include <hip/hip_runtime.h>
#include <math.h>

// MultiHeadAttention: x[1,4096,1024] fp32, Wq/Wk/Wv[1024,1024], Wo[1024,1024].
// Outputs (concat in d_out): y[4096*1024] fp32, attn[8*4096*4096] fp32.
//
// R6 structure (= R5 + single-barrier attn_pv):
//   split x / transpose weights -> Q,K proj (split-bf16, fused z=2 launch),
//   V proj + transpose ->
//   qk_rowsum (split QK, exp, rowsums only -- NO S store) ->
//   attn_pv   (flash-style recompute; ONE barrier/panel via sP dbuf,
//              setprio around MFMA clusters, fused reciprocal;
//              K staged via pre-swizzled global_load_lds, V frags from L2,
//              head-per-XCD grid) ->
//   Wo proj.
// R5 measured: 1020 us total (vs 1169 with expS round-trip). R6 targets the
// ~2x gap between attn_pv (~280 us est) and its ~150 us floor: the 2nd
// per-panel barrier (vmcnt(0) drain of attn stores + K prefetch) is removed.

typedef unsigned short u16;
typedef __attribute__((ext_vector_type(8))) short bf16x8;
typedef __attribute__((ext_vector_type(8))) unsigned short u16x8;
typedef __attribute__((ext_vector_type(4))) float f32x4;

#define SEQ 4096
#define FDIM 1024
#define NHEAD 8
#define DK 128

__device__ __forceinline__ u16 f2bf(float f) {
  unsigned u = __float_as_uint(f);
  u += 0x7fffu + ((u >> 16) & 1u);  // round-to-nearest-even
  return (u16)(u >> 16);
}
__device__ __forceinline__ float bf2f(u16 h) {
  return __uint_as_float(((unsigned)h) << 16);
}

__device__ __forceinline__ void g2l16(const void* g, void* l) {
  __builtin_amdgcn_global_load_lds(
      (const __attribute__((address_space(1))) void*)g,
      (__attribute__((address_space(3))) void*)l, 16, 0, 0);
}

// ---------------------------------------------------------------- prep kernels

__global__ void split_f32_bf16(const float4* __restrict__ in, u16* __restrict__ ohi,
                               u16* __restrict__ olo, int n4) {
  int i = blockIdx.x * 256 + threadIdx.x;
  if (i >= n4) return;
  float4 v = in[i];
  u16 h0 = f2bf(v.x), h1 = f2bf(v.y), h2 = f2bf(v.z), h3 = f2bf(v.w);
  u16 l0 = f2bf(v.x - bf2f(h0)), l1 = f2bf(v.y - bf2f(h1));
  u16 l2 = f2bf(v.z - bf2f(h2)), l3 = f2bf(v.w - bf2f(h3));
  *(ushort4*)(ohi + 4 * (size_t)i) = make_ushort4(h0, h1, h2, h3);
  *(ushort4*)(olo + 4 * (size_t)i) = make_ushort4(l0, l1, l2, l3);
}

// out[n][k] = in[k][n], 1024x1024, optional split
__global__ void transpose_split_w(const float* __restrict__ in, u16* __restrict__ ohi,
                                  u16* __restrict__ olo, int dim, int do_split) {
  __shared__ float t[32][33];
  int tx = threadIdx.x, ty = threadIdx.y;
  int x = blockIdx.x * 32 + tx;
  int y0 = blockIdx.y * 32;
  for (int j = ty; j < 32; j += 8) t[j][tx] = in[(long)(y0 + j) * dim + x];
  __syncthreads();
  int x2 = y0 + tx;
  int y2 = blockIdx.x * 32;
  for (int j = ty; j < 32; j += 8) {
    float v = t[tx][j];
    u16 hi = f2bf(v);
    ohi[(long)(y2 + j) * dim + x2] = hi;
    if (do_split) olo[(long)(y2 + j) * dim + x2] = f2bf(v - bf2f(hi));
  }
}

__global__ void transpose_bf16(const u16* __restrict__ in, u16* __restrict__ out,
                               int rows, int cols) {
  __shared__ u16 t[32][33];
  int tx = threadIdx.x, ty = threadIdx.y;
  int x = blockIdx.x * 32 + tx;
  int y0 = blockIdx.y * 32;
  for (int j = ty; j < 32; j += 8) t[j][tx] = in[(long)(y0 + j) * cols + x];
  __syncthreads();
  int x2 = y0 + tx;
  int y2 = blockIdx.x * 32;
  for (int j = ty; j < 32; j += 8) out[(long)(y2 + j) * rows + x2] = t[tx][j];
}

// ---------------------------------------------------------------- projection GEMM (C = A * B^T)
// EPI: 0 = fp32 store, 1 = bf16 store, 2 = split bf16 store
template <int BK, bool SPLIT, int EPI>
__global__ __launch_bounds__(256, 2) void gemm_bt(
    const u16* Ahi_, const u16* Alo_,
    const u16* Bhi_, const u16* Blo_,
    void* C0, void* C1,
    int Kdim, int lda, int ldb, int ldc,
    long aStrH, long bStrH, long cStrH) {
  constexpr int LDSN = 128 * BK;
  __shared__ u16 sAhi[LDSN];
  __shared__ u16 sBhi[LDSN];
  __shared__ u16 sAlo[SPLIT ? LDSN : 2];
  __shared__ u16 sBlo[SPLIT ? LDSN : 2];

  const int tid = threadIdx.x;
  const int lane = tid & 63;
  const int wave = tid >> 6;
  const int wr = wave >> 1, wc = wave & 1;
  const int quad = lane >> 4, l16 = lane & 15;
  const int h = blockIdx.z;
  const long bm = (long)blockIdx.y * 128;
  const long bn = (long)blockIdx.x * 128;

  const u16* Ahi = Ahi_ + (long)h * aStrH;
  const u16* Alo = SPLIT ? (Alo_ + (long)h * aStrH) : nullptr;
  const u16* Bhi = Bhi_ + (long)h * bStrH;
  const u16* Blo = SPLIT ? (Blo_ + (long)h * bStrH) : nullptr;

  f32x4 acc[4][4];
#pragma unroll
  for (int i = 0; i < 4; i++)
#pragma unroll
    for (int j = 0; j < 4; j++) acc[i][j] = (f32x4)0.0f;

  for (int k0 = 0; k0 < Kdim; k0 += BK) {
    constexpr int GR = (128 * BK) / (256 * 8);
#pragma unroll
    for (int r = 0; r < GR; ++r) {
      int e = (r * 256 + tid) * 8;
      int row = e / BK, col = e % BK;
      long ga = (bm + row) * (long)lda + k0 + col;
      long gb = (bn + row) * (long)ldb + k0 + col;
      g2l16(Ahi + ga, (char*)sAhi + (size_t)e * 2);
      g2l16(Bhi + gb, (char*)sBhi + (size_t)e * 2);
      if constexpr (SPLIT) {
        g2l16(Alo + ga, (char*)sAlo + (size_t)e * 2);
        g2l16(Blo + gb, (char*)sBlo + (size_t)e * 2);
      }
    }
    __syncthreads();

#pragma unroll
    for (int ks = 0; ks < BK; ks += 32) {
      bf16x8 aH[4], bH[4];
      bf16x8 aL[SPLIT ? 4 : 1], bL[SPLIT ? 4 : 1];
#pragma unroll
      for (int mi = 0; mi < 4; mi++) {
        int off = (wr * 64 + mi * 16 + l16) * BK + ks + quad * 8;
        aH[mi] = *(const bf16x8*)&sAhi[off];
        if constexpr (SPLIT) aL[mi] = *(const bf16x8*)&sAlo[off];
      }
#pragma unroll
      for (int ni = 0; ni < 4; ni++) {
        int off = (wc * 64 + ni * 16 + l16) * BK + ks + quad * 8;
        bH[ni] = *(const bf16x8*)&sBhi[off];
        if constexpr (SPLIT) bL[ni] = *(const bf16x8*)&sBlo[off];
      }
#pragma unroll
      for (int mi = 0; mi < 4; mi++)
#pragma unroll
        for (int ni = 0; ni < 4; ni++) {
          acc[mi][ni] = __builtin_amdgcn_mfma_f32_16x16x32_bf16(aH[mi], bH[ni], acc[mi][ni], 0, 0, 0);
          if constexpr (SPLIT) {
            acc[mi][ni] = __builtin_amdgcn_mfma_f32_16x16x32_bf16(aH[mi], bL[ni], acc[mi][ni], 0, 0, 0);
            acc[mi][ni] = __builtin_amdgcn_mfma_f32_16x16x32_bf16(aL[mi], bH[ni], acc[mi][ni], 0, 0, 0);
          }
        }
    }
    __syncthreads();
  }

  const long rowB = bm + wr * 64;
  const long colB = bn + wc * 64;
  if constexpr (EPI == 2) {
    u16* Chi = (u16*)C0 + (long)h * cStrH;
    u16* Clo = (u16*)C1 + (long)h * cStrH;
#pragma unroll
    for (int mi = 0; mi < 4; mi++)
#pragma unroll
      for (int ni = 0; ni < 4; ni++) {
        long col = colB + ni * 16 + l16;
#pragma unroll
        for (int r = 0; r < 4; r++) {
          long idx = (rowB + mi * 16 + quad * 4 + r) * (long)ldc + col;
          float v = acc[mi][ni][r];
          u16 hi = f2bf(v);
          Chi[idx] = hi;
          Clo[idx] = f2bf(v - bf2f(hi));
        }
      }
  } else if constexpr (EPI == 1) {
    u16* C = (u16*)C0 + (long)h * cStrH;
#pragma unroll
    for (int mi = 0; mi < 4; mi++)
#pragma unroll
      for (int ni = 0; ni < 4; ni++) {
        long col = colB + ni * 16 + l16;
#pragma unroll
        for (int r = 0; r < 4; r++)
          C[(rowB + mi * 16 + quad * 4 + r) * (long)ldc + col] = f2bf(acc[mi][ni][r]);
      }
  } else {
    float* C = (float*)C0 + (long)h * cStrH;
#pragma unroll
    for (int mi = 0; mi < 4; mi++)
#pragma unroll
      for (int ni = 0; ni < 4; ni++) {
        long col = colB + ni * 16 + l16;
#pragma unroll
        for (int r = 0; r < 4; r++)
          C[(rowB + mi * 16 + quad * 4 + r) * (long)ldc + col] = acc[mi][ni][r];
      }
  }
}

// ---------------------------------------------------------------- pass 1: QK^T rowsums
// rowSum[h][s] += sum_t exp(scale * (Q K^T)[s][t]); NO S store.
// Identical split-MFMA accumulation sequence as attn_pv so exp values match
// bit-for-bit between passes.
__global__ __launch_bounds__(256, 2) void qk_rowsum(
    const u16* __restrict__ Qhi, const u16* __restrict__ Qlo,
    const u16* __restrict__ Khi, const u16* __restrict__ Klo,
    float* __restrict__ rowSum, float scale) {
  __shared__ u16 smem[32768];  // 64 KB staging
  u16* sQh = smem;
  u16* sQl = smem + 8192;
  u16* sKh = smem + 16384;
  u16* sKl = smem + 24576;

  const int tid = threadIdx.x;
  const int lane = tid & 63, wave = tid >> 6;
  const int wr = wave >> 1, wc = wave & 1;
  const int quad = lane >> 4, l16 = lane & 15;
  const int h = blockIdx.z;
  const int bm = blockIdx.y * 128, bn = blockIdx.x * 128;
  const int colOff = h * DK;

  f32x4 acc[4][4];
#pragma unroll
  for (int i = 0; i < 4; i++)
#pragma unroll
    for (int j = 0; j < 4; j++) acc[i][j] = (f32x4)0.0f;

  for (int k0 = 0; k0 < DK; k0 += 64) {
#pragma unroll
    for (int r = 0; r < 4; ++r) {
      int e = (r * 256 + tid) * 8;
      int row = e >> 6, col = e & 63;
      long gq = (long)(bm + row) * FDIM + colOff + k0 + col;
      long gk = (long)(bn + row) * FDIM + colOff + k0 + col;
      g2l16(Qhi + gq, (char*)sQh + (size_t)e * 2);
      g2l16(Qlo + gq, (char*)sQl + (size_t)e * 2);
      g2l16(Khi + gk, (char*)sKh + (size_t)e * 2);
      g2l16(Klo + gk, (char*)sKl + (size_t)e * 2);
    }
    __syncthreads();
#pragma unroll
    for (int ks = 0; ks < 64; ks += 32) {
      bf16x8 aH[4], aL[4], bH[4], bL[4];
#pragma unroll
      for (int i = 0; i < 4; i++) {
        int offA = (wr * 64 + i * 16 + l16) * 64 + ks + quad * 8;
        int offB = (wc * 64 + i * 16 + l16) * 64 + ks + quad * 8;
        aH[i] = *(const bf16x8*)&sQh[offA];
        aL[i] = *(const bf16x8*)&sQl[offA];
        bH[i] = *(const bf16x8*)&sKh[offB];
        bL[i] = *(const bf16x8*)&sKl[offB];
      }
#pragma unroll
      for (int mi = 0; mi < 4; mi++)
#pragma unroll
        for (int ni = 0; ni < 4; ni++) {
          acc[mi][ni] = __builtin_amdgcn_mfma_f32_16x16x32_bf16(aH[mi], bH[ni], acc[mi][ni], 0, 0, 0);
          acc[mi][ni] = __builtin_amdgcn_mfma_f32_16x16x32_bf16(aH[mi], bL[ni], acc[mi][ni], 0, 0, 0);
          acc[mi][ni] = __builtin_amdgcn_mfma_f32_16x16x32_bf16(aL[mi], bH[ni], acc[mi][ni], 0, 0, 0);
        }
    }
    __syncthreads();
  }

  // exp + per-row sums (shfl over the 16 col-lanes, atomic per block)
#pragma unroll
  for (int mi = 0; mi < 4; mi++) {
    f32x4 rs = (f32x4)0.0f;
#pragma unroll
    for (int ni = 0; ni < 4; ni++)
#pragma unroll
      for (int r = 0; r < 4; r++) rs[r] += __expf(acc[mi][ni][r] * scale);
#pragma unroll
    for (int m = 1; m < 16; m <<= 1) {
      rs[0] += __shfl_xor(rs[0], m);
      rs[1] += __shfl_xor(rs[1], m);
      rs[2] += __shfl_xor(rs[2], m);
      rs[3] += __shfl_xor(rs[3], m);
    }
    if (l16 == 0) {
      int rbase = h * SEQ + bm + wr * 64 + mi * 16 + quad * 4;
#pragma unroll
      for (int r = 0; r < 4; r++) atomicAdd(&rowSum[rbase + r], rs[r]);
    }
  }
}

// ---------------------------------------------------------------- pass 2: fused attn + PV
// Per block: 64-row panel of head h. Sweep 64-col K-panels: recompute S
// (split, bit-identical to pass 1), P = exp(S*scale)/rowSum -> swizzled sP
// (bf16, double-buffered); write attn fp32 from sP (coalesced); y += P @ V.
// R6: ONE barrier per panel (sP dbuf removes the trailing barrier, so attn
// stores and the K prefetch are never force-drained mid-panel), setprio
// around both MFMA clusters, reciprocal fused into the rowSum load.
// LDS: K dbuf 64 KB + sP dbuf 16 KB = 80 KB -> 2 blocks/CU.
__global__ __launch_bounds__(256, 2) void attn_pv(
    const u16* __restrict__ Qhi, const u16* __restrict__ Qlo,
    const u16* __restrict__ Khi, const u16* __restrict__ Klo,
    const u16* __restrict__ Vt, const float* __restrict__ rowSum,
    float* __restrict__ attn, u16* __restrict__ Yb, float scale) {
  __shared__ u16 sKh[2][8192];  // [64 rows][128 dk] bf16, swizzled; x2 dbuf
  __shared__ u16 sKl[2][8192];
  __shared__ u16 sP[2][4096];   // [64][64] bf16, swizzled; x2 dbuf

  const int tid = threadIdx.x;
  const int lane = tid & 63, wave = tid >> 6;
  const int wr = wave >> 1, wc = wave & 1;
  const int quad = lane >> 4, l16 = lane & 15;
  const int h = blockIdx.x;   // head on blockIdx.x -> linear id % 8 == h -> head-per-XCD
  const int bm = blockIdx.y * 64;
  const int colOff = h * DK;

  // Q fragments in registers (loaded once): A-frag row = bm+wr*32+mi*16+l16,
  // k-chunk = kk*32 + quad*8.  16 x bf16x8 = 64 VGPR.
  bf16x8 qH[2][4], qL[2][4];
#pragma unroll
  for (int mi = 0; mi < 2; mi++)
#pragma unroll
    for (int kk = 0; kk < 4; kk++) {
      long g = (long)(bm + wr * 32 + mi * 16 + l16) * FDIM + colOff + kk * 32 + quad * 8;
      qH[mi][kk] = *(const bf16x8*)(Qhi + g);
      qL[mi][kk] = *(const bf16x8*)(Qlo + g);
    }

  // per-thread normalizers for the 8 S-rows this thread produces (fused recip)
  float invr[2][4];
#pragma unroll
  for (int mi = 0; mi < 2; mi++)
#pragma unroll
    for (int rr = 0; rr < 4; rr++)
      invr[mi][rr] = 1.0f / rowSum[(long)h * SEQ + bm + wr * 32 + mi * 16 + quad * 4 + rr];

  f32x4 yacc[2][4];
#pragma unroll
  for (int i = 0; i < 2; i++)
#pragma unroll
    for (int j = 0; j < 4; j++) yacc[i][j] = (f32x4)0.0f;

  const long attnRowBase = ((long)h * SEQ + bm) * (long)SEQ;

  // stage K panel bn -> buf: linear LDS dest, pre-swizzled global source.
  // physical 16B chunk c: row = c>>4, logical col-chunk = (c&15) ^ (row&7).
  auto STAGEK = [&](int bn, int buf) {
#pragma unroll
    for (int r = 0; r < 4; ++r) {
      int c = r * 256 + tid;
      int row = c >> 4;
      int jl = (c & 15) ^ (row & 7);
      long g = (long)(bn + row) * FDIM + colOff + jl * 8;
      g2l16(Khi + g, (char*)sKh[buf] + (size_t)c * 16);
      g2l16(Klo + g, (char*)sKl[buf] + (size_t)c * 16);
    }
  };

  STAGEK(0, 0);
  __syncthreads();

  int cur = 0;
  for (int it = 0; it < 64; ++it) {
    const int bn = it * 64;
    const int pbuf = it & 1;
    if (it < 63) STAGEK(bn + 64, cur ^ 1);  // async; drains at this panel's barrier

    // V fragments for this panel, direct from global (L2-resident per XCD);
    // issued early so latency hides under the QK MFMA cluster.
    bf16x8 vfr[4][2];
#pragma unroll
    for (int ni = 0; ni < 4; ni++)
#pragma unroll
      for (int ks = 0; ks < 2; ks++)
        vfr[ni][ks] = *(const bf16x8*)(
            Vt + (long)(colOff + wc * 64 + ni * 16 + l16) * SEQ + bn + ks * 32 + quad * 8);

    // ---- QK^T (split hi/lo, 3 MFMA; same k-chunk order as qk_rowsum)
    f32x4 sacc[2][2];
#pragma unroll
    for (int i = 0; i < 2; i++) {
      sacc[i][0] = (f32x4)0.0f;
      sacc[i][1] = (f32x4)0.0f;
    }
    __builtin_amdgcn_s_setprio(1);
#pragma unroll
    for (int kk = 0; kk < 4; kk++) {
      bf16x8 bH[2], bL[2];
#pragma unroll
      for (int ni = 0; ni < 2; ni++) {
        int krow = wc * 32 + ni * 16 + l16;
        int byo = (krow * 256 + kk * 64 + quad * 16) ^ ((krow & 7) << 4);
        bH[ni] = *(const bf16x8*)((const char*)sKh[cur] + byo);
        bL[ni] = *(const bf16x8*)((const char*)sKl[cur] + byo);
      }
#pragma unroll
      for (int mi = 0; mi < 2; mi++)
#pragma unroll
        for (int ni = 0; ni < 2; ni++) {
          sacc[mi][ni] = __builtin_amdgcn_mfma_f32_16x16x32_bf16(qH[mi][kk], bH[ni], sacc[mi][ni], 0, 0, 0);
          sacc[mi][ni] = __builtin_amdgcn_mfma_f32_16x16x32_bf16(qH[mi][kk], bL[ni], sacc[mi][ni], 0, 0, 0);
          sacc[mi][ni] = __builtin_amdgcn_mfma_f32_16x16x32_bf16(qL[mi][kk], bH[ni], sacc[mi][ni], 0, 0, 0);
        }
    }
    __builtin_amdgcn_s_setprio(0);

    // ---- P = exp(S*scale) * invRow -> sP[pbuf] (swizzled bf16)
#pragma unroll
    for (int mi = 0; mi < 2; mi++)
#pragma unroll
      for (int ni = 0; ni < 2; ni++)
#pragma unroll
        for (int rr = 0; rr < 4; rr++) {
          int prow = wr * 32 + mi * 16 + quad * 4 + rr;
          int pcol = wc * 32 + ni * 16 + l16;
          float pv = __expf(sacc[mi][ni][rr] * scale) * invr[mi][rr];
          int byo = (prow * 128 + pcol * 2) ^ ((prow & 7) << 4);
          *(u16*)((char*)sP[pbuf] + byo) = f2bf(pv);
        }
    __syncthreads();  // sP[pbuf] + next-K visible; prior stores/prefetch drain here

    // ---- y += P @ V   (readers of sP[pbuf]; next iter writes sP[pbuf^1])
    __builtin_amdgcn_s_setprio(1);
#pragma unroll
    for (int ks = 0; ks < 2; ks++) {
      bf16x8 a[2];
#pragma unroll
      for (int mi = 0; mi < 2; mi++) {
        int prow = wr * 32 + mi * 16 + l16;
        int byo = (prow * 128 + ks * 64 + quad * 16) ^ ((prow & 7) << 4);
        a[mi] = *(const bf16x8*)((const char*)sP[pbuf] + byo);
      }
#pragma unroll
      for (int mi = 0; mi < 2; mi++)
#pragma unroll
        for (int ni = 0; ni < 4; ni++)
          yacc[mi][ni] = __builtin_amdgcn_mfma_f32_16x16x32_bf16(a[mi], vfr[ni][ks], yacc[mi][ni], 0, 0, 0);
    }
    __builtin_amdgcn_s_setprio(0);

    // ---- attn tile store (fp32, coalesced, from sP[pbuf]); fire-and-forget
#pragma unroll
    for (int half = 0; half < 2; ++half) {
      int e = half * 2048 + tid * 8;
      int r = e >> 6, c8 = e & 63;
      int byo = (r * 128 + c8 * 2) ^ ((r & 7) << 4);
      u16x8 u = *(const u16x8*)((const char*)sP[pbuf] + byo);
      long g = attnRowBase + (long)r * SEQ + bn + c8;
      *(float4*)(attn + g) = make_float4(bf2f(u[0]), bf2f(u[1]), bf2f(u[2]), bf2f(u[3]));
      *(float4*)(attn + g + 4) = make_float4(bf2f(u[4]), bf2f(u[5]), bf2f(u[6]), bf2f(u[7]));
    }
    cur ^= 1;  // no trailing barrier: next panel writes sP[pbuf^1] / sK[cur^1]
  }

  // ---- y epilogue (bf16 Yb for the Wo GEMM)
#pragma unroll
  for (int mi = 0; mi < 2; mi++)
#pragma unroll
    for (int ni = 0; ni < 4; ni++)
#pragma unroll
      for (int r = 0; r < 4; r++) {
        long row = bm + wr * 32 + mi * 16 + quad * 4 + r;
        int col = colOff + wc * 64 + ni * 16 + l16;
        Yb[row * (long)FDIM + col] = f2bf(yacc[mi][ni][r]);
      }
}

// ---------------------------------------------------------------- launcher

extern "C" void kernel_launch(void* const* d_in, const int* in_sizes, int n_in,
                              void* d_out, int out_size, void* d_ws, size_t ws_size,
                              hipStream_t stream) {
  const float* x = (const float*)d_in[0];
  const float* Wq = (const float*)d_in[1];
  const float* Wk = (const float*)d_in[2];
  const float* Wv = (const float*)d_in[3];
  const float* Wo = (const float*)d_in[4];

  float* outY = (float*)d_out;              // 4096*1024
  float* attn = outY + (size_t)SEQ * FDIM;  // 8*4096*4096

  const size_t NX = (size_t)SEQ * FDIM;   // 4194304
  const size_t NW = (size_t)FDIM * FDIM;  // 1048576

  u16* p = (u16*)d_ws;
  u16* xhi = p; p += NX;
  u16* xlo = p; p += NX;
  u16* wqt_h = p; p += NW;
  u16* wqt_l = p; p += NW;
  u16* wkt_h = p; p += NW;   // wqt_h + 2*NW (z-stride for fused QK proj)
  u16* wkt_l = p; p += NW;
  u16* wvt = p; p += NW;
  u16* wot = p; p += NW;
  u16* Qhi = p; p += NX;
  u16* Qlo = p; p += NX;
  u16* Khi = p; p += NX;     // Qhi + 2*NX
  u16* Klo = p; p += NX;
  u16* Vb = p; p += NX;
  u16* Vt = p; p += NX;
  u16* Yb = p; p += NX;
  float* rowSum = (float*)p;

  hipMemsetAsync(rowSum, 0, (size_t)NHEAD * SEQ * sizeof(float), stream);

  split_f32_bf16<<<dim3((NX / 4 + 255) / 256), 256, 0, stream>>>(
      (const float4*)x, xhi, xlo, NX / 4);

  dim3 tb(32, 8);
  transpose_split_w<<<dim3(32, 32), tb, 0, stream>>>(Wq, wqt_h, wqt_l, FDIM, 1);
  transpose_split_w<<<dim3(32, 32), tb, 0, stream>>>(Wk, wkt_h, wkt_l, FDIM, 1);
  transpose_split_w<<<dim3(32, 32), tb, 0, stream>>>(Wv, wvt, nullptr, FDIM, 0);
  transpose_split_w<<<dim3(32, 32), tb, 0, stream>>>(Wo, wot, nullptr, FDIM, 0);

  // Q and K projections fused (z=0 -> Q, z=1 -> K), split in/out
  gemm_bt<32, true, 2><<<dim3(8, 32, 2), 256, 0, stream>>>(
      xhi, xlo, wqt_h, wqt_l, Qhi, Qlo,
      1024, 1024, 1024, 1024, 0, (long)2 * NW, (long)2 * NX);

  // V projection (plain bf16) + transpose
  gemm_bt<64, false, 1><<<dim3(8, 32, 1), 256, 0, stream>>>(
      xhi, nullptr, wvt, nullptr, Vb, nullptr,
      1024, 1024, 1024, 1024, 0, 0, 0);
  transpose_bf16<<<dim3(32, 128), tb, 0, stream>>>(Vb, Vt, SEQ, FDIM);

  const float scale = 0.08838834764831845f;  // 1/sqrt(128)

  // pass 1: rowsums only (no S store)
  qk_rowsum<<<dim3(32, 32, NHEAD), 256, 0, stream>>>(
      Qhi, Qlo, Khi, Klo, rowSum, scale);

  // pass 2: recompute S, write attn, accumulate y = P @ V (recip fused)
  attn_pv<<<dim3(NHEAD, 64, 1), 256, 0, stream>>>(
      Qhi, Qlo, Khi, Klo, Vt, rowSum, attn, Yb, scale);

  // out = y @ Wo
  gemm_bt<64, false, 0><<<dim3(8, 32, 1), 256, 0, stream>>>(
      Yb, nullptr, wot, nullptr, outY, nullptr,
      1024, 1024, 1024, 1024, 0, 0, 0);
}